// Round 12
// baseline (369.042 us; speedup 1.0000x reference)
//
#include <hip/hip_runtime.h>

#define NROW  8192      // B*T
#define D_    1024
#define E_    2048
#define P2E_  4096
#define CD_   256
#define NC_   1024
#define BETA_ 0.25f
#define SPLITK 4

typedef __attribute__((ext_vector_type(8))) short short8;
typedef __attribute__((ext_vector_type(4))) float f32x4;

__device__ __forceinline__ ushort f2bf(float x) {
    union { float f; unsigned u; } v; v.f = x;
    unsigned r = (v.u + 0x7fffu + ((v.u >> 16) & 1u)) >> 16;
    return (ushort)r;
}
__device__ __forceinline__ float bf2f(ushort h) {
    union { unsigned u; float f; } v; v.u = ((unsigned)h) << 16;
    return v.f;
}
__device__ __forceinline__ void split2(float x, ushort& h, ushort& l) {
    h = f2bf(x);
    l = f2bf(x - bf2f(h));
}
__device__ __forceinline__ float gelu_tanh(float x) {
    float x3 = x * x * x;
    return 0.5f * x * (1.0f + tanhf(0.7978845608028654f * (x + 0.044715f * x3)));
}

// async global->LDS, 16B per lane
#define GLD16(gp, lp) __builtin_amdgcn_global_load_lds( \
    (const __attribute__((address_space(1))) void*)(gp), \
    (__attribute__((address_space(3))) void*)(lp), 16, 0, 0)

// ---------------------------------------------------------------------------
// Split-bf16 (3-term) MFMA GEMM.  C = A @ B^T = Ah.Bh + Ah.Bl + Al.Bh (fp32 acc)
// A: M x K row-major (hi/lo bf16), B: N x K row-major (hi/lo bf16).
// Tile 128x128, BK=32, **128 threads = 2 waves (1M x 2N), wave tile 128x64**.
// R12 change (single variable vs R11): 4 waves -> 2 waves per block. The 2x2
// wave grid read every A/B frag twice from LDS (64 KB frags + 32 KB staging =
// 384 cy vs 233 cy MFMA -> 61% cap, measured 47.5). 1Mx2N reads A once per
// wave (48+32 KB = 324 cy) -> cap 72%. Schedule/LDS/swizzle/grid UNCHANGED:
//   iter s: ds_read 24 frags -> barrier -> STAGE(next tile) -> 96 MFMA
//   (loads fly under MFMAs) -> barrier (vmcnt(0) drain)
// Regs: 24 frags (96 V) + acc 8x4 (128 A) + addr ~ 248 <= 256 -> 2 waves/SIMD,
// 4 blocks/CU (>= the 3-block floor this family needs).
// LDS XOR swizzle on 16B slots (both-sides: pre-swizzled global src + ds_read).
// EPI 0: gelu(x + bias[n]) -> split -> Ph/Pl with concat layout (GEMM1)
// EPI 1: partial fp32 -> outF[z*NROW + m][n]  (GEMM2, split-K via blockIdx.z)
// EPI 2: dists (rn[m] - 2x) + cn[n] -> outF[m*NC_+n]  (GEMM3)
// ---------------------------------------------------------------------------
template<int EPI>
__global__ __launch_bounds__(128, 2)
void gemm_bf16x3(const ushort* __restrict__ Ah, const ushort* __restrict__ Al,
                 const ushort* __restrict__ Bh, const ushort* __restrict__ Bl,
                 int K, int ksteps,
                 const float* __restrict__ bias,
                 float* __restrict__ outF,
                 ushort* __restrict__ oPh, ushort* __restrict__ oPl,
                 const float* __restrict__ rn, const float* __restrict__ cn)
{
    __shared__ alignas(16) ushort sAh[4096], sAl[4096], sBh[4096], sBl[4096];
    const int t = threadIdx.x;      // 0..127
    const int l = t & 63;
    const int w = t >> 6;           // 0..1 (N-wave)

    // bijective XCD chunk swizzle (all grids have gridDim.x*gridDim.y % 8 == 0)
    const int nxy = gridDim.x * gridDim.y;
    const int id  = blockIdx.y * gridDim.x + blockIdx.x;
    const int swz = (id & 7) * (nxy >> 3) + (id >> 3);
    const int bx  = swz % gridDim.x;
    const int by  = swz / gridDim.x;

    const int bm = by * 128;
    const int bn = bx * 128;
    const int kstart = (EPI == 1) ? (int)blockIdx.z * (ksteps * 32) : 0;

    // staging: 4 passes x 16B per thread per matrix tile (128 thr); pass p
    // covers rows p*32 + (t>>2). global source pre-swizzled:
    // slot' = slot ^ ((row>>1)&3) = (t&3) ^ ((t>>3)&3)   (p*32 rows: p*16%4==0)
    const int srow = t >> 2;                       // 0..31
    const int scol = ((t & 3) ^ ((t >> 3) & 3)) * 8;
    const ushort* gAh = Ah + (size_t)(bm + srow) * K + kstart + scol;
    const ushort* gAl = Al + (size_t)(bm + srow) * K + kstart + scol;
    const ushort* gBh = Bh + (size_t)(bn + srow) * K + kstart + scol;
    const ushort* gBl = Bl + (size_t)(bn + srow) * K + kstart + scol;
    const size_t rstep = (size_t)32 * K;           // 32 rows per pass
    const int d8 = t * 8;                          // + p*1024 per pass

    f32x4 acc[8][4];
#pragma unroll
    for (int i = 0; i < 8; i++)
#pragma unroll
        for (int j = 0; j < 4; j++) acc[i][j] = (f32x4)0.0f;

    // swizzled ds_read: row*32 + (kq ^ ((row>>1)&3))*8; (row>>1)&3 == (lr>>1)&3
    const int kq = l >> 4, lr = l & 15;
    const int rsw = (kq ^ ((lr >> 1) & 3)) * 8;
    const int ar = lr * 32 + rsw;                  // A row = i*16 + lr -> + i*512
    const int br = (w * 64 + lr) * 32 + rsw;       // B col = w*64 + j*16 + lr -> + j*512

#define STAGE16() do { \
        _Pragma("unroll") \
        for (int p = 0; p < 4; p++) { \
            GLD16(gAh + p * rstep, &sAh[p * 1024 + d8]); \
            GLD16(gAl + p * rstep, &sAl[p * 1024 + d8]); \
            GLD16(gBh + p * rstep, &sBh[p * 1024 + d8]); \
            GLD16(gBl + p * rstep, &sBl[p * 1024 + d8]); \
        } } while (0)

    STAGE16();                // tile 0
    __syncthreads();          // vmcnt(0) drain: tile 0 resident

    for (int s = 0; s < ksteps; ++s) {
        short8 fah[8], fal[8], fbh[4], fbl[4];
#pragma unroll
        for (int i = 0; i < 8; i++) {
            fah[i] = *(const short8*)&sAh[ar + i * 512];
            fal[i] = *(const short8*)&sAl[ar + i * 512];
        }
#pragma unroll
        for (int j = 0; j < 4; j++) {
            fbh[j] = *(const short8*)&sBh[br + j * 512];
            fbl[j] = *(const short8*)&sBl[br + j * 512];
        }
        __syncthreads();      // all waves done reading this tile (lgkm drained)

        if (s + 1 < ksteps) { // issue next tile's loads; they fly under the MFMAs
            gAh += 32; gAl += 32; gBh += 32; gBl += 32;
            STAGE16();
        }

        __builtin_amdgcn_s_setprio(1);
#pragma unroll
        for (int i = 0; i < 8; i++)
#pragma unroll
            for (int j = 0; j < 4; j++) {
                acc[i][j] = __builtin_amdgcn_mfma_f32_16x16x32_bf16(fah[i], fbh[j], acc[i][j], 0, 0, 0);
                acc[i][j] = __builtin_amdgcn_mfma_f32_16x16x32_bf16(fah[i], fbl[j], acc[i][j], 0, 0, 0);
                acc[i][j] = __builtin_amdgcn_mfma_f32_16x16x32_bf16(fal[i], fbh[j], acc[i][j], 0, 0, 0);
            }
        __builtin_amdgcn_s_setprio(0);
        __syncthreads();      // vmcnt(0): next tile resident
    }
#undef STAGE16

    // epilogue: C frag -> row = i*16 + kq*4 + r, col = w*64 + j*16 + lr
#pragma unroll
    for (int i = 0; i < 8; i++) {
        const int grow = bm + i * 16 + kq * 4;
#pragma unroll
        for (int j = 0; j < 4; j++) {
            const int gcol = bn + w * 64 + j * 16 + lr;
            f32x4 a = acc[i][j];
            if constexpr (EPI == 0) {
                const float bb = bias[gcol];
#pragma unroll
                for (int r = 0; r < 4; r++) {
                    int m = grow + r;
                    float x = gelu_tanh(a[r] + bb);
                    ushort h, lo; split2(x, h, lo);
                    int pr = (m < NROW) ? m : m - NROW;
                    int pc = ((m < NROW) ? 0 : E_) + gcol;
                    oPh[(size_t)pr * P2E_ + pc] = h;
                    oPl[(size_t)pr * P2E_ + pc] = lo;
                }
            } else if constexpr (EPI == 1) {
                float* o = outF + ((size_t)NROW * blockIdx.z + grow) * CD_ + gcol;
#pragma unroll
                for (int r = 0; r < 4; r++) o[(size_t)r * CD_] = a[r];
            } else {
#pragma unroll
                for (int r = 0; r < 4; r++) {
                    int m = grow + r;
                    outF[(size_t)m * NC_ + gcol] = (rn[m] - 2.0f * a[r]) + cn[gcol];
                }
            }
        }
    }
}

// elementwise fp32 -> (hi,lo) bf16 over TWO source tensors in one launch
__global__ void split2_k(const float* __restrict__ a, const float* __restrict__ b,
                         ushort* __restrict__ oh, ushort* __restrict__ ol, int n4each)
{
    int i = blockIdx.x * blockDim.x + threadIdx.x;
    int stride = gridDim.x * blockDim.x;
    for (; i < 2 * n4each; i += stride) {
        float4 v = (i < n4each) ? ((const float4*)a)[i] : ((const float4*)b)[i - n4each];
        ushort4 h, lo;
        split2(v.x, h.x, lo.x); split2(v.y, h.y, lo.y);
        split2(v.z, h.z, lo.z); split2(v.w, h.w, lo.w);
        ((ushort4*)oh)[i] = h;
        ((ushort4*)ol)[i] = lo;
    }
}

// elementwise fp32 -> (hi,lo) bf16 (single tensor)
__global__ void split_k(const float* __restrict__ in, ushort* __restrict__ oh,
                        ushort* __restrict__ ol, int n4)
{
    int i = blockIdx.x * blockDim.x + threadIdx.x;
    int stride = gridDim.x * blockDim.x;
    for (; i < n4; i += stride) {
        float4 v = ((const float4*)in)[i];
        ushort4 h, lo;
        split2(v.x, h.x, lo.x); split2(v.y, h.y, lo.y);
        split2(v.z, h.z, lo.z); split2(v.w, h.w, lo.w);
        ((ushort4*)oh)[i] = h;
        ((ushort4*)ol)[i] = lo;
    }
}

// transpose + split: in R x C fp32 -> out C x R (hi,lo) bf16
__global__ __launch_bounds__(1024)
void tsplit_k(const float* __restrict__ in, ushort* __restrict__ oh,
              ushort* __restrict__ ol, int R, int C)
{
    __shared__ float tile[32][33];
    int c0 = blockIdx.x * 32, r0 = blockIdx.y * 32;
    int tx = threadIdx.x, ty = threadIdx.y;
    tile[ty][tx] = in[(size_t)(r0 + ty) * C + c0 + tx];
    __syncthreads();
    float x = tile[tx][ty];
    ushort h, lo; split2(x, h, lo);
    size_t o = (size_t)(c0 + ty) * R + r0 + tx;
    oh[o] = h; ol[o] = lo;
}

// sum split-K partials + bias -> latent fp32, hi/lo bf16, row norms
__global__ __launch_bounds__(256)
void combine_k(const float* __restrict__ part, const float* __restrict__ bias,
               float* __restrict__ latent, ushort* __restrict__ lh,
               ushort* __restrict__ ll, float* __restrict__ rown)
{
    __shared__ float red[256];
    int row = blockIdx.x, t = threadIdx.x;
    float x = bias[t];
#pragma unroll
    for (int z = 0; z < SPLITK; z++) x += part[((size_t)z * NROW + row) * CD_ + t];
    latent[(size_t)row * CD_ + t] = x;
    ushort h, lo; split2(x, h, lo);
    lh[(size_t)row * CD_ + t] = h;
    ll[(size_t)row * CD_ + t] = lo;
    red[t] = x * x;
    __syncthreads();
    for (int st = 128; st > 0; st >>= 1) { if (t < st) red[t] += red[t + st]; __syncthreads(); }
    if (t == 0) rown[row] = red[0];
}

// ||row||^2 (256-col matrix) + zero hist[n] (grid == NC_ == hist size)
__global__ __launch_bounds__(256) void row_norms_zh(const float* __restrict__ X,
                                                    float* __restrict__ out,
                                                    int* __restrict__ hist)
{
    __shared__ float s[256];
    int n = blockIdx.x, t = threadIdx.x;
    float v = X[(size_t)n * 256 + t];
    s[t] = v * v;
    __syncthreads();
    for (int st = 128; st > 0; st >>= 1) {
        if (t < st) s[t] += s[t + st];
        __syncthreads();
    }
    if (t == 0) { out[n] = s[0]; hist[n] = 0; }
}

// One block per latent row. dists_enc holds dists on entry; overwritten with one-hot.
__global__ __launch_bounds__(256) void vq_kernel(
    const float* __restrict__ latent, const float* __restrict__ cb,
    float* __restrict__ dists_enc, float* __restrict__ out_q,
    float* __restrict__ out_idx, int* __restrict__ hist, float* __restrict__ lpart)
{
    __shared__ float sd[256];
    __shared__ int   si[256];
    const int n = blockIdx.x, tid = threadIdx.x;
    float* drow = dists_enc + (size_t)n * NC_;

    float best = INFINITY;
    int bidx = 0;
#pragma unroll
    for (int j = 0; j < NC_ / 256; j++) {
        int c = tid + j * 256;
        float d = drow[c];
        if (d < best) { best = d; bidx = c; }
    }
    sd[tid] = best; si[tid] = bidx;
    __syncthreads();
    for (int st = 128; st > 0; st >>= 1) {
        if (tid < st) {
            float d2 = sd[tid + st]; int i2 = si[tid + st];
            if (d2 < sd[tid] || (d2 == sd[tid] && i2 < si[tid])) { sd[tid] = d2; si[tid] = i2; }
        }
        __syncthreads();
    }
    const int bc = si[0];

#pragma unroll
    for (int j = 0; j < NC_ / 256; j++) {
        int c = tid + j * 256;
        drow[c] = (c == bc) ? 1.0f : 0.0f;
    }

    float lv = latent[(size_t)n * CD_ + tid];
    float q  = cb[(size_t)bc * CD_ + tid];
    out_q[(size_t)n * CD_ + tid] = lv + (q - lv);
    float diff = q - lv;
    __syncthreads();
    sd[tid] = diff * diff;
    __syncthreads();
    for (int st = 128; st > 0; st >>= 1) {
        if (tid < st) sd[tid] += sd[tid + st];
        __syncthreads();
    }
    if (tid == 0) {
        lpart[n] = sd[0];
        atomicAdd(&hist[bc], 1);
        out_idx[n] = (float)bc;
    }
}

__global__ __launch_bounds__(1024) void finalize_kernel(
    const float* __restrict__ lpart, const int* __restrict__ hist,
    float* __restrict__ out_loss, float* __restrict__ out_perp)
{
    __shared__ float s[1024];
    int t = threadIdx.x;
    float x = 0.0f;
    for (int i = t; i < NROW; i += 1024) x += lpart[i];
    s[t] = x;
    __syncthreads();
    for (int st = 512; st > 0; st >>= 1) {
        if (t < st) s[t] += s[t + st];
        __syncthreads();
    }
    float total = s[0];
    __syncthreads();
    float p = (float)hist[t] * (1.0f / NROW);
    s[t] = p * logf(p + 1e-10f);
    __syncthreads();
    for (int st = 512; st > 0; st >>= 1) {
        if (t < st) s[t] += s[t + st];
        __syncthreads();
    }
    if (t == 0) {
        *out_loss = BETA_ * (total / (float)((size_t)NROW * CD_));
        *out_perp = expf(-s[0]);
    }
}

extern "C" void kernel_launch(void* const* d_in, const int* in_sizes, int n_in,
                              void* d_out, int out_size, void* d_ws, size_t ws_size,
                              hipStream_t stream)
{
    const float* states      = (const float*)d_in[0];
    const float* next_states = (const float*)d_in[1];
    const float* W_s         = (const float*)d_in[2];
    const float* b_s         = (const float*)d_in[3];
    const float* W_p         = (const float*)d_in[4];
    const float* b_p         = (const float*)d_in[5];
    const float* codebook    = (const float*)d_in[6];

    float* out      = (float*)d_out;
    float* out_q    = out;
    float* out_loss = out + (size_t)NROW * CD_;
    float* out_perp = out_loss + 1;
    float* out_enc  = out_perp + 1;                  // dists scratch -> one-hot
    float* out_idx  = out_enc + (size_t)NROW * NC_;

    char* ws = (char*)d_ws;
    size_t off = 0;
    auto alloc = [&](size_t bytes) { void* p = ws + off; off += (bytes + 255) & ~255ull; return p; };

    ushort* A1h  = (ushort*)alloc((size_t)2 * NROW * D_ * 2);   // 32 MiB
    ushort* A1l  = (ushort*)alloc((size_t)2 * NROW * D_ * 2);   // 32 MiB
    ushort* WsTh = (ushort*)alloc((size_t)E_ * D_ * 2);
    ushort* WsTl = (ushort*)alloc((size_t)E_ * D_ * 2);
    ushort* WpTh = (ushort*)alloc((size_t)CD_ * P2E_ * 2);
    ushort* WpTl = (ushort*)alloc((size_t)CD_ * P2E_ * 2);
    ushort* cbh  = (ushort*)alloc((size_t)NC_ * CD_ * 2);
    ushort* cbl  = (ushort*)alloc((size_t)NC_ * CD_ * 2);
    ushort* Ph   = (ushort*)alloc((size_t)NROW * P2E_ * 2);     // 64 MiB
    ushort* Pl   = (ushort*)alloc((size_t)NROW * P2E_ * 2);
    ushort* lath = (ushort*)alloc((size_t)NROW * CD_ * 2);
    ushort* latl = (ushort*)alloc((size_t)NROW * CD_ * 2);
    float*  rown = (float*)alloc(NROW * 4);
    float*  cbn  = (float*)alloc(NC_ * 4);
    int*    hist = (int*)alloc(NC_ * 4);
    float*  lpart= (float*)alloc(NROW * 4);
    // aliases over dead regions (A1/WsT dead after GEMM1):
    float* lat_part = (float*)A1h;    // SPLITK*8192*256*4 = 32 MiB in A1h
    float* latent   = (float*)WsTh;   // 8 MiB over WsTh+WsTl

    // --- conversions ---
    split2_k<<<4096, 256, 0, stream>>>(states, next_states, A1h, A1l, NROW * D_ / 4);
    tsplit_k<<<dim3(E_ / 32, D_ / 32), dim3(32, 32), 0, stream>>>(W_s, WsTh, WsTl, D_, E_);
    tsplit_k<<<dim3(CD_ / 32, P2E_ / 32), dim3(32, 32), 0, stream>>>(W_p, WpTh, WpTl, P2E_, CD_);
    split_k<<<256, 256, 0, stream>>>(codebook, cbh, cbl, NC_ * CD_ / 4);
    row_norms_zh<<<NC_, 256, 0, stream>>>(codebook, cbn, hist);

    // --- GEMM1: P = gelu([states;next_states] @ W_s + b_s), concat layout, split hi/lo ---
    gemm_bf16x3<0><<<dim3(E_ / 128, 2 * NROW / 128), 128, 0, stream>>>(
        A1h, A1l, WsTh, WsTl, D_, D_ / 32, b_s, nullptr, Ph, Pl, nullptr, nullptr);

    // --- GEMM2: latent partials (split-K = 4) ---
    gemm_bf16x3<1><<<dim3(CD_ / 128, NROW / 128, SPLITK), 128, 0, stream>>>(
        Ph, Pl, WpTh, WpTl, P2E_, P2E_ / 32 / SPLITK, nullptr, lat_part, nullptr, nullptr,
        nullptr, nullptr);

    // --- combine: bias + fp32 latent + hi/lo + row norms ---
    combine_k<<<NROW, 256, 0, stream>>>(lat_part, b_p, latent, lath, latl, rown);

    // --- GEMM3: dists into encodings region ---
    gemm_bf16x3<2><<<dim3(NC_ / 128, NROW / 128), 128, 0, stream>>>(
        lath, latl, cbh, cbl, CD_, CD_ / 32, nullptr, out_enc, nullptr, nullptr,
        rown, cbn);

    // --- VQ: argmin, one-hot (in place), quantize_st, loss partials, histogram ---
    vq_kernel<<<NROW, 256, 0, stream>>>(latent, codebook, out_enc, out_q, out_idx, hist, lpart);

    // --- scalars ---
    finalize_kernel<<<1, 1024, 0, stream>>>(lpart, hist, out_loss, out_perp);
}

// Round 13
// 346.554 us; speedup vs baseline: 1.0649x; 1.0649x over previous
//
#include <hip/hip_runtime.h>

#define NROW  8192      // B*T
#define D_    1024
#define E_    2048
#define P2E_  4096
#define CD_   256
#define NC_   1024
#define BETA_ 0.25f
#define SPLITK 4

typedef __attribute__((ext_vector_type(8))) short short8;
typedef __attribute__((ext_vector_type(4))) float f32x4;

__device__ __forceinline__ ushort f2bf(float x) {
    union { float f; unsigned u; } v; v.f = x;
    unsigned r = (v.u + 0x7fffu + ((v.u >> 16) & 1u)) >> 16;
    return (ushort)r;
}
__device__ __forceinline__ float bf2f(ushort h) {
    union { unsigned u; float f; } v; v.u = ((unsigned)h) << 16;
    return v.f;
}
__device__ __forceinline__ void split2(float x, ushort& h, ushort& l) {
    h = f2bf(x);
    l = f2bf(x - bf2f(h));
}
__device__ __forceinline__ float gelu_tanh(float x) {
    float x3 = x * x * x;
    return 0.5f * x * (1.0f + tanhf(0.7978845608028654f * (x + 0.044715f * x3)));
}

// async global->LDS, 16B per lane
#define GLD16(gp, lp) __builtin_amdgcn_global_load_lds( \
    (const __attribute__((address_space(1))) void*)(gp), \
    (__attribute__((address_space(3))) void*)(lp), 16, 0, 0)

// ---------------------------------------------------------------------------
// Split-bf16 (3-term) MFMA GEMM.  C = A @ B^T = Ah.Bh + Ah.Bl + Al.Bh (fp32 acc)
// A: M x K row-major (hi/lo bf16), B: N x K row-major (hi/lo bf16).
// Tile 128x128, BK=32, 256 threads = 4 waves (2x2), each wave 64x64 (4x4 frags).
// MEASURED-OPTIMAL structure (R11: GEMM1 207us, MfmaUtil 47.5%, conflicts 0;
// ALL structural variants regressed: dbuf(R4), 3-ring counted-vmcnt(R6),
// 8 light waves(R7), B-direct(R8), 256x128(R9), 2-buf counted-vmcnt(R10),
// 2-wave 128-thr(R12) -> 34-44% MfmaUtil each. The 2-barrier drain schedule
// at >=12 waves/CU is this op's fixed point; ~995 TF effective on GEMM1.)
//   iter s: ds_read frags -> barrier -> STAGE(next tile) -> MFMA (loads fly
//   under MFMAs) -> barrier (vmcnt(0) drain)
// Single 32KB LDS buffer keeps >=3 blocks/CU resident (the controlling
// variable: <=2 blocks/CU always measured 38-44% MfmaUtil, >=3 gives 47%).
// LDS XOR swizzle on 16B slots (both-sides: pre-swizzled global src + ds_read).
// EPI 0: gelu(x + bias[n]) -> split -> Ph/Pl with concat layout (GEMM1)
// EPI 1: partial fp32 -> outF[z*NROW + m][n]  (GEMM2, split-K via blockIdx.z)
// EPI 2: dists (rn[m] - 2x) + cn[n] -> outF[m*NC_+n]  (GEMM3)
// ---------------------------------------------------------------------------
template<int EPI>
__global__ __launch_bounds__(256)
void gemm_bf16x3(const ushort* __restrict__ Ah, const ushort* __restrict__ Al,
                 const ushort* __restrict__ Bh, const ushort* __restrict__ Bl,
                 int K, int ksteps,
                 const float* __restrict__ bias,
                 float* __restrict__ outF,
                 ushort* __restrict__ oPh, ushort* __restrict__ oPl,
                 const float* __restrict__ rn, const float* __restrict__ cn)
{
    __shared__ alignas(16) ushort sAh[4096], sAl[4096], sBh[4096], sBl[4096];
    const int t = threadIdx.x;
    const int l = t & 63;
    const int w = t >> 6;
    const int wr = w >> 1, wc = w & 1;

    // bijective XCD chunk swizzle (all grids have gridDim.x*gridDim.y % 8 == 0)
    const int nxy = gridDim.x * gridDim.y;
    const int id  = blockIdx.y * gridDim.x + blockIdx.x;
    const int swz = (id & 7) * (nxy >> 3) + (id >> 3);
    const int bx  = swz % gridDim.x;
    const int by  = swz / gridDim.x;

    const int bm = by * 128;
    const int bn = bx * 128;
    const int kstart = (EPI == 1) ? (int)blockIdx.z * (ksteps * 32) : 0;

    // staging: 2 passes x 16B per thread per matrix tile; LDS dest linear (t*16B).
    // global source pre-swizzled: slot' = slot ^ ((row>>1)&3), row = t>>2 (+64)
    const int srow = t >> 2;                       // 0..63
    const int scol = ((t & 3) ^ ((t >> 3) & 3)) * 8;
    const ushort* gAh = Ah + (size_t)(bm + srow) * K + kstart + scol;
    const ushort* gAl = Al + (size_t)(bm + srow) * K + kstart + scol;
    const ushort* gBh = Bh + (size_t)(bn + srow) * K + kstart + scol;
    const ushort* gBl = Bl + (size_t)(bn + srow) * K + kstart + scol;
    const size_t rstep = (size_t)64 * K;
    const int lo0 = t * 8, lo1 = t * 8 + 2048;

    f32x4 acc[4][4];
#pragma unroll
    for (int i = 0; i < 4; i++)
#pragma unroll
        for (int j = 0; j < 4; j++) acc[i][j] = (f32x4)0.0f;

    // swizzled ds_read address: row = wr*64 + i*16 + (l&15); slot = (l>>4) ^ ((row>>1)&3)
    const int rsw = ((l >> 4) ^ (((l & 15) >> 1) & 3)) * 8;
    const int ar = (wr * 64 + (l & 15)) * 32 + rsw;
    const int br = (wc * 64 + (l & 15)) * 32 + rsw;

#define STAGE8() do { \
        GLD16(gAh, &sAh[lo0]); GLD16(gAh + rstep, &sAh[lo1]); \
        GLD16(gAl, &sAl[lo0]); GLD16(gAl + rstep, &sAl[lo1]); \
        GLD16(gBh, &sBh[lo0]); GLD16(gBh + rstep, &sBh[lo1]); \
        GLD16(gBl, &sBl[lo0]); GLD16(gBl + rstep, &sBl[lo1]); \
    } while (0)

    STAGE8();                 // tile 0
    __syncthreads();          // vmcnt(0) drain: tile 0 resident

    for (int s = 0; s < ksteps; ++s) {
        short8 fah[4], fal[4], fbh[4], fbl[4];
#pragma unroll
        for (int i = 0; i < 4; i++) {
            fah[i] = *(const short8*)&sAh[ar + i * 16 * 32];
            fal[i] = *(const short8*)&sAl[ar + i * 16 * 32];
            fbh[i] = *(const short8*)&sBh[br + i * 16 * 32];
            fbl[i] = *(const short8*)&sBl[br + i * 16 * 32];
        }
        __syncthreads();      // all waves done reading this tile (lgkm drained)

        if (s + 1 < ksteps) { // issue next tile's loads; they fly under the MFMAs
            gAh += 32; gAl += 32; gBh += 32; gBl += 32;
            STAGE8();
        }

        __builtin_amdgcn_s_setprio(1);
#pragma unroll
        for (int i = 0; i < 4; i++)
#pragma unroll
            for (int j = 0; j < 4; j++) {
                acc[i][j] = __builtin_amdgcn_mfma_f32_16x16x32_bf16(fah[i], fbh[j], acc[i][j], 0, 0, 0);
                acc[i][j] = __builtin_amdgcn_mfma_f32_16x16x32_bf16(fah[i], fbl[j], acc[i][j], 0, 0, 0);
                acc[i][j] = __builtin_amdgcn_mfma_f32_16x16x32_bf16(fal[i], fbh[j], acc[i][j], 0, 0, 0);
            }
        __builtin_amdgcn_s_setprio(0);
        __syncthreads();      // vmcnt(0): next tile resident
    }
#undef STAGE8

    // epilogue: C frag -> row = 4*(l>>4)+r, col = l&15  (m89-verified layout)
#pragma unroll
    for (int i = 0; i < 4; i++) {
        const int grow = bm + wr * 64 + i * 16 + (l >> 4) * 4;
#pragma unroll
        for (int j = 0; j < 4; j++) {
            const int gcol = bn + wc * 64 + j * 16 + (l & 15);
            f32x4 a = acc[i][j];
            if constexpr (EPI == 0) {
                const float bb = bias[gcol];
#pragma unroll
                for (int r = 0; r < 4; r++) {
                    int m = grow + r;
                    float x = gelu_tanh(a[r] + bb);
                    ushort h, lo; split2(x, h, lo);
                    int pr = (m < NROW) ? m : m - NROW;
                    int pc = ((m < NROW) ? 0 : E_) + gcol;
                    oPh[(size_t)pr * P2E_ + pc] = h;
                    oPl[(size_t)pr * P2E_ + pc] = lo;
                }
            } else if constexpr (EPI == 1) {
                float* o = outF + ((size_t)NROW * blockIdx.z + grow) * CD_ + gcol;
#pragma unroll
                for (int r = 0; r < 4; r++) o[(size_t)r * CD_] = a[r];
            } else {
#pragma unroll
                for (int r = 0; r < 4; r++) {
                    int m = grow + r;
                    outF[(size_t)m * NC_ + gcol] = (rn[m] - 2.0f * a[r]) + cn[gcol];
                }
            }
        }
    }
}

// elementwise fp32 -> (hi,lo) bf16 over TWO source tensors in one launch
__global__ void split2_k(const float* __restrict__ a, const float* __restrict__ b,
                         ushort* __restrict__ oh, ushort* __restrict__ ol, int n4each)
{
    int i = blockIdx.x * blockDim.x + threadIdx.x;
    int stride = gridDim.x * blockDim.x;
    for (; i < 2 * n4each; i += stride) {
        float4 v = (i < n4each) ? ((const float4*)a)[i] : ((const float4*)b)[i - n4each];
        ushort4 h, lo;
        split2(v.x, h.x, lo.x); split2(v.y, h.y, lo.y);
        split2(v.z, h.z, lo.z); split2(v.w, h.w, lo.w);
        ((ushort4*)oh)[i] = h;
        ((ushort4*)ol)[i] = lo;
    }
}

// elementwise fp32 -> (hi,lo) bf16 (single tensor)
__global__ void split_k(const float* __restrict__ in, ushort* __restrict__ oh,
                        ushort* __restrict__ ol, int n4)
{
    int i = blockIdx.x * blockDim.x + threadIdx.x;
    int stride = gridDim.x * blockDim.x;
    for (; i < n4; i += stride) {
        float4 v = ((const float4*)in)[i];
        ushort4 h, lo;
        split2(v.x, h.x, lo.x); split2(v.y, h.y, lo.y);
        split2(v.z, h.z, lo.z); split2(v.w, h.w, lo.w);
        ((ushort4*)oh)[i] = h;
        ((ushort4*)ol)[i] = lo;
    }
}

// transpose + split: in R x C fp32 -> out C x R (hi,lo) bf16
__global__ __launch_bounds__(1024)
void tsplit_k(const float* __restrict__ in, ushort* __restrict__ oh,
              ushort* __restrict__ ol, int R, int C)
{
    __shared__ float tile[32][33];
    int c0 = blockIdx.x * 32, r0 = blockIdx.y * 32;
    int tx = threadIdx.x, ty = threadIdx.y;
    tile[ty][tx] = in[(size_t)(r0 + ty) * C + c0 + tx];
    __syncthreads();
    float x = tile[tx][ty];
    ushort h, lo; split2(x, h, lo);
    size_t o = (size_t)(c0 + ty) * R + r0 + tx;
    oh[o] = h; ol[o] = lo;
}

// sum split-K partials + bias -> latent fp32, hi/lo bf16, row norms
__global__ __launch_bounds__(256)
void combine_k(const float* __restrict__ part, const float* __restrict__ bias,
               float* __restrict__ latent, ushort* __restrict__ lh,
               ushort* __restrict__ ll, float* __restrict__ rown)
{
    __shared__ float red[256];
    int row = blockIdx.x, t = threadIdx.x;
    float x = bias[t];
#pragma unroll
    for (int z = 0; z < SPLITK; z++) x += part[((size_t)z * NROW + row) * CD_ + t];
    latent[(size_t)row * CD_ + t] = x;
    ushort h, lo; split2(x, h, lo);
    lh[(size_t)row * CD_ + t] = h;
    ll[(size_t)row * CD_ + t] = lo;
    red[t] = x * x;
    __syncthreads();
    for (int st = 128; st > 0; st >>= 1) { if (t < st) red[t] += red[t + st]; __syncthreads(); }
    if (t == 0) rown[row] = red[0];
}

// ||row||^2 (256-col matrix) + zero hist[n] (grid == NC_ == hist size)
__global__ __launch_bounds__(256) void row_norms_zh(const float* __restrict__ X,
                                                    float* __restrict__ out,
                                                    int* __restrict__ hist)
{
    __shared__ float s[256];
    int n = blockIdx.x, t = threadIdx.x;
    float v = X[(size_t)n * 256 + t];
    s[t] = v * v;
    __syncthreads();
    for (int st = 128; st > 0; st >>= 1) {
        if (t < st) s[t] += s[t + st];
        __syncthreads();
    }
    if (t == 0) { out[n] = s[0]; hist[n] = 0; }
}

// One block per latent row. dists_enc holds dists on entry; overwritten with one-hot.
__global__ __launch_bounds__(256) void vq_kernel(
    const float* __restrict__ latent, const float* __restrict__ cb,
    float* __restrict__ dists_enc, float* __restrict__ out_q,
    float* __restrict__ out_idx, int* __restrict__ hist, float* __restrict__ lpart)
{
    __shared__ float sd[256];
    __shared__ int   si[256];
    const int n = blockIdx.x, tid = threadIdx.x;
    float* drow = dists_enc + (size_t)n * NC_;

    float best = INFINITY;
    int bidx = 0;
#pragma unroll
    for (int j = 0; j < NC_ / 256; j++) {
        int c = tid + j * 256;
        float d = drow[c];
        if (d < best) { best = d; bidx = c; }
    }
    sd[tid] = best; si[tid] = bidx;
    __syncthreads();
    for (int st = 128; st > 0; st >>= 1) {
        if (tid < st) {
            float d2 = sd[tid + st]; int i2 = si[tid + st];
            if (d2 < sd[tid] || (d2 == sd[tid] && i2 < si[tid])) { sd[tid] = d2; si[tid] = i2; }
        }
        __syncthreads();
    }
    const int bc = si[0];

#pragma unroll
    for (int j = 0; j < NC_ / 256; j++) {
        int c = tid + j * 256;
        drow[c] = (c == bc) ? 1.0f : 0.0f;
    }

    float lv = latent[(size_t)n * CD_ + tid];
    float q  = cb[(size_t)bc * CD_ + tid];
    out_q[(size_t)n * CD_ + tid] = lv + (q - lv);
    float diff = q - lv;
    __syncthreads();
    sd[tid] = diff * diff;
    __syncthreads();
    for (int st = 128; st > 0; st >>= 1) {
        if (tid < st) sd[tid] += sd[tid + st];
        __syncthreads();
    }
    if (tid == 0) {
        lpart[n] = sd[0];
        atomicAdd(&hist[bc], 1);
        out_idx[n] = (float)bc;
    }
}

__global__ __launch_bounds__(1024) void finalize_kernel(
    const float* __restrict__ lpart, const int* __restrict__ hist,
    float* __restrict__ out_loss, float* __restrict__ out_perp)
{
    __shared__ float s[1024];
    int t = threadIdx.x;
    float x = 0.0f;
    for (int i = t; i < NROW; i += 1024) x += lpart[i];
    s[t] = x;
    __syncthreads();
    for (int st = 512; st > 0; st >>= 1) {
        if (t < st) s[t] += s[t + st];
        __syncthreads();
    }
    float total = s[0];
    __syncthreads();
    float p = (float)hist[t] * (1.0f / NROW);
    s[t] = p * logf(p + 1e-10f);
    __syncthreads();
    for (int st = 512; st > 0; st >>= 1) {
        if (t < st) s[t] += s[t + st];
        __syncthreads();
    }
    if (t == 0) {
        *out_loss = BETA_ * (total / (float)((size_t)NROW * CD_));
        *out_perp = expf(-s[0]);
    }
}

extern "C" void kernel_launch(void* const* d_in, const int* in_sizes, int n_in,
                              void* d_out, int out_size, void* d_ws, size_t ws_size,
                              hipStream_t stream)
{
    const float* states      = (const float*)d_in[0];
    const float* next_states = (const float*)d_in[1];
    const float* W_s         = (const float*)d_in[2];
    const float* b_s         = (const float*)d_in[3];
    const float* W_p         = (const float*)d_in[4];
    const float* b_p         = (const float*)d_in[5];
    const float* codebook    = (const float*)d_in[6];

    float* out      = (float*)d_out;
    float* out_q    = out;
    float* out_loss = out + (size_t)NROW * CD_;
    float* out_perp = out_loss + 1;
    float* out_enc  = out_perp + 1;                  // dists scratch -> one-hot
    float* out_idx  = out_enc + (size_t)NROW * NC_;

    char* ws = (char*)d_ws;
    size_t off = 0;
    auto alloc = [&](size_t bytes) { void* p = ws + off; off += (bytes + 255) & ~255ull; return p; };

    ushort* A1h  = (ushort*)alloc((size_t)2 * NROW * D_ * 2);   // 32 MiB
    ushort* A1l  = (ushort*)alloc((size_t)2 * NROW * D_ * 2);   // 32 MiB
    ushort* WsTh = (ushort*)alloc((size_t)E_ * D_ * 2);
    ushort* WsTl = (ushort*)alloc((size_t)E_ * D_ * 2);
    ushort* WpTh = (ushort*)alloc((size_t)CD_ * P2E_ * 2);
    ushort* WpTl = (ushort*)alloc((size_t)CD_ * P2E_ * 2);
    ushort* cbh  = (ushort*)alloc((size_t)NC_ * CD_ * 2);
    ushort* cbl  = (ushort*)alloc((size_t)NC_ * CD_ * 2);
    ushort* Ph   = (ushort*)alloc((size_t)NROW * P2E_ * 2);     // 64 MiB
    ushort* Pl   = (ushort*)alloc((size_t)NROW * P2E_ * 2);
    ushort* lath = (ushort*)alloc((size_t)NROW * CD_ * 2);
    ushort* latl = (ushort*)alloc((size_t)NROW * CD_ * 2);
    float*  rown = (float*)alloc(NROW * 4);
    float*  cbn  = (float*)alloc(NC_ * 4);
    int*    hist = (int*)alloc(NC_ * 4);
    float*  lpart= (float*)alloc(NROW * 4);
    // aliases over dead regions (A1/WsT dead after GEMM1):
    float* lat_part = (float*)A1h;    // SPLITK*8192*256*4 = 32 MiB in A1h
    float* latent   = (float*)WsTh;   // 8 MiB over WsTh+WsTl

    // --- conversions ---
    split2_k<<<4096, 256, 0, stream>>>(states, next_states, A1h, A1l, NROW * D_ / 4);
    tsplit_k<<<dim3(E_ / 32, D_ / 32), dim3(32, 32), 0, stream>>>(W_s, WsTh, WsTl, D_, E_);
    tsplit_k<<<dim3(CD_ / 32, P2E_ / 32), dim3(32, 32), 0, stream>>>(W_p, WpTh, WpTl, P2E_, CD_);
    split_k<<<256, 256, 0, stream>>>(codebook, cbh, cbl, NC_ * CD_ / 4);
    row_norms_zh<<<NC_, 256, 0, stream>>>(codebook, cbn, hist);

    // --- GEMM1: P = gelu([states;next_states] @ W_s + b_s), concat layout, split hi/lo ---
    gemm_bf16x3<0><<<dim3(E_ / 128, 2 * NROW / 128), 256, 0, stream>>>(
        A1h, A1l, WsTh, WsTl, D_, D_ / 32, b_s, nullptr, Ph, Pl, nullptr, nullptr);

    // --- GEMM2: latent partials (split-K = 4) ---
    gemm_bf16x3<1><<<dim3(CD_ / 128, NROW / 128, SPLITK), 256, 0, stream>>>(
        Ph, Pl, WpTh, WpTl, P2E_, P2E_ / 32 / SPLITK, nullptr, lat_part, nullptr, nullptr,
        nullptr, nullptr);

    // --- combine: bias + fp32 latent + hi/lo + row norms ---
    combine_k<<<NROW, 256, 0, stream>>>(lat_part, b_p, latent, lath, latl, rown);

    // --- GEMM3: dists into encodings region ---
    gemm_bf16x3<2><<<dim3(NC_ / 128, NROW / 128), 256, 0, stream>>>(
        lath, latl, cbh, cbl, CD_, CD_ / 32, nullptr, out_enc, nullptr, nullptr,
        rown, cbn);

    // --- VQ: argmin, one-hot (in place), quantize_st, loss partials, histogram ---
    vq_kernel<<<NROW, 256, 0, stream>>>(latent, codebook, out_enc, out_q, out_idx, hist, lpart);

    // --- scalars ---
    finalize_kernel<<<1, 1024, 0, stream>>>(lpart, hist, out_loss, out_perp);
}

// Round 15
// 342.021 us; speedup vs baseline: 1.0790x; 1.0133x over previous
//
#include <hip/hip_runtime.h>

#define NROW  8192      // B*T
#define D_    1024
#define E_    2048
#define P2E_  4096
#define CD_   256
#define NC_   1024
#define BETA_ 0.25f
#define SPLITK 4

typedef __attribute__((ext_vector_type(8))) short short8;
typedef __attribute__((ext_vector_type(4))) float f32x4;

__device__ __forceinline__ ushort f2bf(float x) {
    union { float f; unsigned u; } v; v.f = x;
    unsigned r = (v.u + 0x7fffu + ((v.u >> 16) & 1u)) >> 16;
    return (ushort)r;
}
__device__ __forceinline__ float bf2f(ushort h) {
    union { unsigned u; float f; } v; v.u = ((unsigned)h) << 16;
    return v.f;
}
__device__ __forceinline__ void split2(float x, ushort& h, ushort& l) {
    h = f2bf(x);
    l = f2bf(x - bf2f(h));
}
__device__ __forceinline__ float gelu_tanh(float x) {
    float x3 = x * x * x;
    return 0.5f * x * (1.0f + tanhf(0.7978845608028654f * (x + 0.044715f * x3)));
}

// async global->LDS, 16B per lane
#define GLD16(gp, lp) __builtin_amdgcn_global_load_lds( \
    (const __attribute__((address_space(1))) void*)(gp), \
    (__attribute__((address_space(3))) void*)(lp), 16, 0, 0)

// ---------------------------------------------------------------------------
// Split-bf16 (3-term) MFMA GEMM.  C = A @ B^T = Ah.Bh + Ah.Bl + Al.Bh (fp32 acc)
// A: M x K row-major (hi/lo bf16), B: N x K row-major (hi/lo bf16).
// Tile 128x128, BK=32, 256 threads = 4 waves (2x2), each wave 64x64 (4x4 frags).
// MEASURED-OPTIMAL structure (R11/R13: GEMM1 207us, MfmaUtil 47.5%, 0 bank
// conflicts, ~995 TF effective). All structural variants regressed or raced:
// dbuf(R4), 3-ring counted-vmcnt(R6), 8 light waves(R7), B-direct(R8),
// 256x128(R9), 2-buf counted-vmcnt(R10), 2-wave(R12), fine 3-phase(R14 RACE).
// The 2-barrier drain schedule at >=12 waves/CU is this op's fixed point.
//   iter s: ds_read frags -> barrier -> STAGE(next tile) -> MFMA (loads fly
//   under MFMAs) -> barrier (vmcnt(0) drain)
// Single 32KB LDS buffer keeps >=3 blocks/CU resident (the controlling
// variable: <=2 blocks/CU always measured 34-44% MfmaUtil, >=3 gives 47%).
// LDS XOR swizzle on 16B slots (both-sides: pre-swizzled global src + ds_read).
// EPI 0: gelu(x + bias[n]) -> split -> Ph/Pl with concat layout (GEMM1)
// EPI 1: partial fp32 -> outF[z*NROW + m][n]  (GEMM2, split-K via blockIdx.z)
// EPI 2: dists (rn[m] - 2x) + cn[n] -> outF[m*NC_+n]  (GEMM3)
// ---------------------------------------------------------------------------
template<int EPI>
__global__ __launch_bounds__(256)
void gemm_bf16x3(const ushort* __restrict__ Ah, const ushort* __restrict__ Al,
                 const ushort* __restrict__ Bh, const ushort* __restrict__ Bl,
                 int K, int ksteps,
                 const float* __restrict__ bias,
                 float* __restrict__ outF,
                 ushort* __restrict__ oPh, ushort* __restrict__ oPl,
                 const float* __restrict__ rn, const float* __restrict__ cn)
{
    __shared__ alignas(16) ushort sAh[4096], sAl[4096], sBh[4096], sBl[4096];
    const int t = threadIdx.x;
    const int l = t & 63;
    const int w = t >> 6;
    const int wr = w >> 1, wc = w & 1;

    // bijective XCD chunk swizzle (all grids have gridDim.x*gridDim.y % 8 == 0)
    const int nxy = gridDim.x * gridDim.y;
    const int id  = blockIdx.y * gridDim.x + blockIdx.x;
    const int swz = (id & 7) * (nxy >> 3) + (id >> 3);
    const int bx  = swz % gridDim.x;
    const int by  = swz / gridDim.x;

    const int bm = by * 128;
    const int bn = bx * 128;
    const int kstart = (EPI == 1) ? (int)blockIdx.z * (ksteps * 32) : 0;

    // staging: 2 passes x 16B per thread per matrix tile; LDS dest linear (t*16B).
    // global source pre-swizzled: slot' = slot ^ ((row>>1)&3), row = t>>2 (+64)
    const int srow = t >> 2;                       // 0..63
    const int scol = ((t & 3) ^ ((t >> 3) & 3)) * 8;
    const ushort* gAh = Ah + (size_t)(bm + srow) * K + kstart + scol;
    const ushort* gAl = Al + (size_t)(bm + srow) * K + kstart + scol;
    const ushort* gBh = Bh + (size_t)(bn + srow) * K + kstart + scol;
    const ushort* gBl = Bl + (size_t)(bn + srow) * K + kstart + scol;
    const size_t rstep = (size_t)64 * K;
    const int lo0 = t * 8, lo1 = t * 8 + 2048;

    f32x4 acc[4][4];
#pragma unroll
    for (int i = 0; i < 4; i++)
#pragma unroll
        for (int j = 0; j < 4; j++) acc[i][j] = (f32x4)0.0f;

    // swizzled ds_read address: row = wr*64 + i*16 + (l&15); slot = (l>>4) ^ ((row>>1)&3)
    const int rsw = ((l >> 4) ^ (((l & 15) >> 1) & 3)) * 8;
    const int ar = (wr * 64 + (l & 15)) * 32 + rsw;
    const int br = (wc * 64 + (l & 15)) * 32 + rsw;

#define STAGE8() do { \
        GLD16(gAh, &sAh[lo0]); GLD16(gAh + rstep, &sAh[lo1]); \
        GLD16(gAl, &sAl[lo0]); GLD16(gAl + rstep, &sAl[lo1]); \
        GLD16(gBh, &sBh[lo0]); GLD16(gBh + rstep, &sBh[lo1]); \
        GLD16(gBl, &sBl[lo0]); GLD16(gBl + rstep, &sBl[lo1]); \
    } while (0)

    STAGE8();                 // tile 0
    __syncthreads();          // vmcnt(0) drain: tile 0 resident

    for (int s = 0; s < ksteps; ++s) {
        short8 fah[4], fal[4], fbh[4], fbl[4];
#pragma unroll
        for (int i = 0; i < 4; i++) {
            fah[i] = *(const short8*)&sAh[ar + i * 16 * 32];
            fal[i] = *(const short8*)&sAl[ar + i * 16 * 32];
            fbh[i] = *(const short8*)&sBh[br + i * 16 * 32];
            fbl[i] = *(const short8*)&sBl[br + i * 16 * 32];
        }
        __syncthreads();      // all waves done reading this tile (lgkm drained)

        if (s + 1 < ksteps) { // issue next tile's loads; they fly under the MFMAs
            gAh += 32; gAl += 32; gBh += 32; gBl += 32;
            STAGE8();
        }

        __builtin_amdgcn_s_setprio(1);
#pragma unroll
        for (int i = 0; i < 4; i++)
#pragma unroll
            for (int j = 0; j < 4; j++) {
                acc[i][j] = __builtin_amdgcn_mfma_f32_16x16x32_bf16(fah[i], fbh[j], acc[i][j], 0, 0, 0);
                acc[i][j] = __builtin_amdgcn_mfma_f32_16x16x32_bf16(fah[i], fbl[j], acc[i][j], 0, 0, 0);
                acc[i][j] = __builtin_amdgcn_mfma_f32_16x16x32_bf16(fal[i], fbh[j], acc[i][j], 0, 0, 0);
            }
        __builtin_amdgcn_s_setprio(0);
        __syncthreads();      // vmcnt(0): next tile resident
    }
#undef STAGE8

    // epilogue: C frag -> row = 4*(l>>4)+r, col = l&15  (m89-verified layout)
#pragma unroll
    for (int i = 0; i < 4; i++) {
        const int grow = bm + wr * 64 + i * 16 + (l >> 4) * 4;
#pragma unroll
        for (int j = 0; j < 4; j++) {
            const int gcol = bn + wc * 64 + j * 16 + (l & 15);
            f32x4 a = acc[i][j];
            if constexpr (EPI == 0) {
                const float bb = bias[gcol];
#pragma unroll
                for (int r = 0; r < 4; r++) {
                    int m = grow + r;
                    float x = gelu_tanh(a[r] + bb);
                    ushort h, lo; split2(x, h, lo);
                    int pr = (m < NROW) ? m : m - NROW;
                    int pc = ((m < NROW) ? 0 : E_) + gcol;
                    oPh[(size_t)pr * P2E_ + pc] = h;
                    oPl[(size_t)pr * P2E_ + pc] = lo;
                }
            } else if constexpr (EPI == 1) {
                float* o = outF + ((size_t)NROW * blockIdx.z + grow) * CD_ + gcol;
#pragma unroll
                for (int r = 0; r < 4; r++) o[(size_t)r * CD_] = a[r];
            } else {
#pragma unroll
                for (int r = 0; r < 4; r++) {
                    int m = grow + r;
                    outF[(size_t)m * NC_ + gcol] = (rn[m] - 2.0f * a[r]) + cn[gcol];
                }
            }
        }
    }
}

// elementwise fp32 -> (hi,lo) bf16 over TWO source tensors in one launch
__global__ void split2_k(const float* __restrict__ a, const float* __restrict__ b,
                         ushort* __restrict__ oh, ushort* __restrict__ ol, int n4each)
{
    int i = blockIdx.x * blockDim.x + threadIdx.x;
    int stride = gridDim.x * blockDim.x;
    for (; i < 2 * n4each; i += stride) {
        float4 v = (i < n4each) ? ((const float4*)a)[i] : ((const float4*)b)[i - n4each];
        ushort4 h, lo;
        split2(v.x, h.x, lo.x); split2(v.y, h.y, lo.y);
        split2(v.z, h.z, lo.z); split2(v.w, h.w, lo.w);
        ((ushort4*)oh)[i] = h;
        ((ushort4*)ol)[i] = lo;
    }
}

// elementwise fp32 -> (hi,lo) bf16 (single tensor)
__global__ void split_k(const float* __restrict__ in, ushort* __restrict__ oh,
                        ushort* __restrict__ ol, int n4)
{
    int i = blockIdx.x * blockDim.x + threadIdx.x;
    int stride = gridDim.x * blockDim.x;
    for (; i < n4; i += stride) {
        float4 v = ((const float4*)in)[i];
        ushort4 h, lo;
        split2(v.x, h.x, lo.x); split2(v.y, h.y, lo.y);
        split2(v.z, h.z, lo.z); split2(v.w, h.w, lo.w);
        ((ushort4*)oh)[i] = h;
        ((ushort4*)ol)[i] = lo;
    }
}

// transpose + split: in R x C fp32 -> out C x R (hi,lo) bf16
__global__ __launch_bounds__(1024)
void tsplit_k(const float* __restrict__ in, ushort* __restrict__ oh,
              ushort* __restrict__ ol, int R, int C)
{
    __shared__ float tile[32][33];
    int c0 = blockIdx.x * 32, r0 = blockIdx.y * 32;
    int tx = threadIdx.x, ty = threadIdx.y;
    tile[ty][tx] = in[(size_t)(r0 + ty) * C + c0 + tx];
    __syncthreads();
    float x = tile[tx][ty];
    ushort h, lo; split2(x, h, lo);
    size_t o = (size_t)(c0 + ty) * R + r0 + tx;
    oh[o] = h; ol[o] = lo;
}

// sum split-K partials + bias -> latent fp32, hi/lo bf16, row norms
__global__ __launch_bounds__(256)
void combine_k(const float* __restrict__ part, const float* __restrict__ bias,
               float* __restrict__ latent, ushort* __restrict__ lh,
               ushort* __restrict__ ll, float* __restrict__ rown)
{
    __shared__ float red[256];
    int row = blockIdx.x, t = threadIdx.x;
    float x = bias[t];
#pragma unroll
    for (int z = 0; z < SPLITK; z++) x += part[((size_t)z * NROW + row) * CD_ + t];
    latent[(size_t)row * CD_ + t] = x;
    ushort h, lo; split2(x, h, lo);
    lh[(size_t)row * CD_ + t] = h;
    ll[(size_t)row * CD_ + t] = lo;
    red[t] = x * x;
    __syncthreads();
    for (int st = 128; st > 0; st >>= 1) { if (t < st) red[t] += red[t + st]; __syncthreads(); }
    if (t == 0) rown[row] = red[0];
}

// ||row||^2 (256-col matrix) + zero hist[n] (grid == NC_ == hist size)
__global__ __launch_bounds__(256) void row_norms_zh(const float* __restrict__ X,
                                                    float* __restrict__ out,
                                                    int* __restrict__ hist)
{
    __shared__ float s[256];
    int n = blockIdx.x, t = threadIdx.x;
    float v = X[(size_t)n * 256 + t];
    s[t] = v * v;
    __syncthreads();
    for (int st = 128; st > 0; st >>= 1) {
        if (t < st) s[t] += s[t + st];
        __syncthreads();
    }
    if (t == 0) { out[n] = s[0]; hist[n] = 0; }
}

// One block per latent row. dists_enc holds dists on entry; overwritten with one-hot.
__global__ __launch_bounds__(256) void vq_kernel(
    const float* __restrict__ latent, const float* __restrict__ cb,
    float* __restrict__ dists_enc, float* __restrict__ out_q,
    float* __restrict__ out_idx, int* __restrict__ hist, float* __restrict__ lpart)
{
    __shared__ float sd[256];
    __shared__ int   si[256];
    const int n = blockIdx.x, tid = threadIdx.x;
    float* drow = dists_enc + (size_t)n * NC_;

    float best = INFINITY;
    int bidx = 0;
#pragma unroll
    for (int j = 0; j < NC_ / 256; j++) {
        int c = tid + j * 256;
        float d = drow[c];
        if (d < best) { best = d; bidx = c; }
    }
    sd[tid] = best; si[tid] = bidx;
    __syncthreads();
    for (int st = 128; st > 0; st >>= 1) {
        if (tid < st) {
            float d2 = sd[tid + st]; int i2 = si[tid + st];
            if (d2 < sd[tid] || (d2 == sd[tid] && i2 < si[tid])) { sd[tid] = d2; si[tid] = i2; }
        }
        __syncthreads();
    }
    const int bc = si[0];

#pragma unroll
    for (int j = 0; j < NC_ / 256; j++) {
        int c = tid + j * 256;
        drow[c] = (c == bc) ? 1.0f : 0.0f;
    }

    float lv = latent[(size_t)n * CD_ + tid];
    float q  = cb[(size_t)bc * CD_ + tid];
    out_q[(size_t)n * CD_ + tid] = lv + (q - lv);
    float diff = q - lv;
    __syncthreads();
    sd[tid] = diff * diff;
    __syncthreads();
    for (int st = 128; st > 0; st >>= 1) {
        if (tid < st) sd[tid] += sd[tid + st];
        __syncthreads();
    }
    if (tid == 0) {
        lpart[n] = sd[0];
        atomicAdd(&hist[bc], 1);
        out_idx[n] = (float)bc;
    }
}

__global__ __launch_bounds__(1024) void finalize_kernel(
    const float* __restrict__ lpart, const int* __restrict__ hist,
    float* __restrict__ out_loss, float* __restrict__ out_perp)
{
    __shared__ float s[1024];
    int t = threadIdx.x;
    float x = 0.0f;
    for (int i = t; i < NROW; i += 1024) x += lpart[i];
    s[t] = x;
    __syncthreads();
    for (int st = 512; st > 0; st >>= 1) {
        if (t < st) s[t] += s[t + st];
        __syncthreads();
    }
    float total = s[0];
    __syncthreads();
    float p = (float)hist[t] * (1.0f / NROW);
    s[t] = p * logf(p + 1e-10f);
    __syncthreads();
    for (int st = 512; st > 0; st >>= 1) {
        if (t < st) s[t] += s[t + st];
        __syncthreads();
    }
    if (t == 0) {
        *out_loss = BETA_ * (total / (float)((size_t)NROW * CD_));
        *out_perp = expf(-s[0]);
    }
}

extern "C" void kernel_launch(void* const* d_in, const int* in_sizes, int n_in,
                              void* d_out, int out_size, void* d_ws, size_t ws_size,
                              hipStream_t stream)
{
    const float* states      = (const float*)d_in[0];
    const float* next_states = (const float*)d_in[1];
    const float* W_s         = (const float*)d_in[2];
    const float* b_s         = (const float*)d_in[3];
    const float* W_p         = (const float*)d_in[4];
    const float* b_p         = (const float*)d_in[5];
    const float* codebook    = (const float*)d_in[6];

    float* out      = (float*)d_out;
    float* out_q    = out;
    float* out_loss = out + (size_t)NROW * CD_;
    float* out_perp = out_loss + 1;
    float* out_enc  = out_perp + 1;                  // dists scratch -> one-hot
    float* out_idx  = out_enc + (size_t)NROW * NC_;

    char* ws = (char*)d_ws;
    size_t off = 0;
    auto alloc = [&](size_t bytes) { void* p = ws + off; off += (bytes + 255) & ~255ull; return p; };

    ushort* A1h  = (ushort*)alloc((size_t)2 * NROW * D_ * 2);   // 32 MiB
    ushort* A1l  = (ushort*)alloc((size_t)2 * NROW * D_ * 2);   // 32 MiB
    ushort* WsTh = (ushort*)alloc((size_t)E_ * D_ * 2);
    ushort* WsTl = (ushort*)alloc((size_t)E_ * D_ * 2);
    ushort* WpTh = (ushort*)alloc((size_t)CD_ * P2E_ * 2);
    ushort* WpTl = (ushort*)alloc((size_t)CD_ * P2E_ * 2);
    ushort* cbh  = (ushort*)alloc((size_t)NC_ * CD_ * 2);
    ushort* cbl  = (ushort*)alloc((size_t)NC_ * CD_ * 2);
    ushort* Ph   = (ushort*)alloc((size_t)NROW * P2E_ * 2);     // 64 MiB
    ushort* Pl   = (ushort*)alloc((size_t)NROW * P2E_ * 2);
    ushort* lath = (ushort*)alloc((size_t)NROW * CD_ * 2);
    ushort* latl = (ushort*)alloc((size_t)NROW * CD_ * 2);
    float*  rown = (float*)alloc(NROW * 4);
    float*  cbn  = (float*)alloc(NC_ * 4);
    int*    hist = (int*)alloc(NC_ * 4);
    float*  lpart= (float*)alloc(NROW * 4);
    // aliases over dead regions (A1/WsT dead after GEMM1):
    float* lat_part = (float*)A1h;    // SPLITK*8192*256*4 = 32 MiB in A1h
    float* latent   = (float*)WsTh;   // 8 MiB over WsTh+WsTl

    // --- conversions ---
    split2_k<<<4096, 256, 0, stream>>>(states, next_states, A1h, A1l, NROW * D_ / 4);
    tsplit_k<<<dim3(E_ / 32, D_ / 32), dim3(32, 32), 0, stream>>>(W_s, WsTh, WsTl, D_, E_);
    tsplit_k<<<dim3(CD_ / 32, P2E_ / 32), dim3(32, 32), 0, stream>>>(W_p, WpTh, WpTl, P2E_, CD_);
    split_k<<<256, 256, 0, stream>>>(codebook, cbh, cbl, NC_ * CD_ / 4);
    row_norms_zh<<<NC_, 256, 0, stream>>>(codebook, cbn, hist);

    // --- GEMM1: P = gelu([states;next_states] @ W_s + b_s), concat layout, split hi/lo ---
    gemm_bf16x3<0><<<dim3(E_ / 128, 2 * NROW / 128), 256, 0, stream>>>(
        A1h, A1l, WsTh, WsTl, D_, D_ / 32, b_s, nullptr, Ph, Pl, nullptr, nullptr);

    // --- GEMM2: latent partials (split-K = 4) ---
    gemm_bf16x3<1><<<dim3(CD_ / 128, NROW / 128, SPLITK), 256, 0, stream>>>(
        Ph, Pl, WpTh, WpTl, P2E_, P2E_ / 32 / SPLITK, nullptr, lat_part, nullptr, nullptr,
        nullptr, nullptr);

    // --- combine: bias + fp32 latent + hi/lo + row norms ---
    combine_k<<<NROW, 256, 0, stream>>>(lat_part, b_p, latent, lath, latl, rown);

    // --- GEMM3: dists into encodings region ---
    gemm_bf16x3<2><<<dim3(NC_ / 128, NROW / 128), 256, 0, stream>>>(
        lath, latl, cbh, cbl, CD_, CD_ / 32, nullptr, out_enc, nullptr, nullptr,
        rown, cbn);

    // --- VQ: argmin, one-hot (in place), quantize_st, loss partials, histogram ---
    vq_kernel<<<NROW, 256, 0, stream>>>(latent, codebook, out_enc, out_q, out_idx, hist, lpart);

    // --- scalars ---
    finalize_kernel<<<1, 1024, 0, stream>>>(lpart, hist, out_loss, out_perp);
}